// Round 3
// baseline (1563.687 us; speedup 1.0000x reference)
//
#include <hip/hip_runtime.h>

// ---------------- problem constants ----------------
#define NVEC  131072      // 32*4096 vectors
#define DIM   64
#define K     512
#define DECAYF 0.99f
#define OMDF   0.01f
#define EPSF   1e-5f

// ---------------- output layout (floats, concatenated in return order) ----
#define Q_OFF    0
#define DIFF_OFF 8388608
#define IND_OFF  8388609
#define NE_OFF   8519681
#define NCS_OFF  8552449
#define NEA_OFF  8552961

// ---------------- ws layout (floats) ----------------
#define ET_OFF    0        // E^T : K x DIM  (code rows contiguous)
#define C_OFF     32768    // np-order sum(E*E, axis=0) : K
#define CNT_OFF   33280    // histogram : K           (written by vq_stats)
#define ESUM_OFF  33792    // segment sum : K x DIM   (written by vq_stats)
#define DSUM_OFF  66560    // diff accumulator : 1    (zeroed each call)

// ============ prep: transpose embed -> E^T, C_j = np.sum(E*E, axis=0) ====
__global__ __launch_bounds__(256) void vq_prep(const float* __restrict__ embed,
                                               float* __restrict__ ws) {
    #pragma clang fp contract(off)
    int j = blockIdx.x * 256 + threadIdx.x;   // code index, 0..511
    float c = 0.0f;
    for (int d = 0; d < DIM; ++d) {
        float v = embed[d * K + j];           // coalesced across j
        ws[ET_OFF + j * DIM + d] = v;
        float t = v * v;
        c = c + t;
    }
    ws[C_OFF + j] = c;
}

// ============ main: np-fp32-replica argmin + quantize + diff ============
// NO stats atomics here — they serialized the whole kernel in round 2
// (WRITE_SIZE 345 MB, VALUBusy 11%). Stats moved to vq_stats.
__global__ __launch_bounds__(256) void vq_assign(
    const float* __restrict__ x,
    const float* __restrict__ ET,      // ws + ET_OFF
    const float* __restrict__ C,       // ws + C_OFF
    float* __restrict__ dsum,
    float* __restrict__ out)
{
    #pragma clang fp contract(off)
    int v = blockIdx.x * 256 + threadIdx.x;
    const float* fx = x + (size_t)v * DIM;

    float f[DIM];
    #pragma unroll
    for (int k = 0; k < DIM / 4; ++k) {
        float4 t = ((const float4*)fx)[k];
        f[4*k+0] = t.x; f[4*k+1] = t.y; f[4*k+2] = t.z; f[4*k+3] = t.w;
    }

    // A = np.sum(f*f, axis=1): numpy pairwise, n=64 -> 8 accumulators over
    // strides of 8, then ((r0+r1)+(r2+r3))+((r4+r5)+(r6+r7)). Plain mul+add.
    float r[8];
    #pragma unroll
    for (int k = 0; k < 8; ++k) r[k] = f[k] * f[k];
    #pragma unroll
    for (int b = 1; b < 8; ++b) {
        #pragma unroll
        for (int k = 0; k < 8; ++k) {
            float t = f[8*b + k] * f[8*b + k];
            r[k] = r[k] + t;
        }
    }
    float A = ((r[0] + r[1]) + (r[2] + r[3])) + ((r[4] + r[5]) + (r[6] + r[7]));

    // dist_j = fl(fl(A - fl(2*M_j)) + C_j), M_j = sequential-fma dot.
    // argmin with strict < ascending j == numpy first-min tie-break.
    // (bit-exact np replica — verified passing in round 2; do not reorder)
    float bestd = 3.0e38f;
    int   besti = 0;
    #pragma unroll 8
    for (int j = 0; j < K; ++j) {
        const float* e = ET + j * DIM;   // j wave-uniform -> scalar loads
        float m = 0.0f;
        #pragma unroll
        for (int d = 0; d < DIM; ++d) m = __builtin_fmaf(f[d], e[d], m);
        float t1 = 2.0f * m;             // exact (x2)
        float t2 = A - t1;               // rounded at ulp(~64)
        float dist = t2 + C[j];          // rounded
        if (dist < bestd) { bestd = dist; besti = j; }
    }

    // outputs: index (as float), quantize row, diff partial
    out[IND_OFF + v] = (float)besti;

    const float* q = ET + (size_t)besti * DIM;   // divergent gather, cache-hot
    float dl = 0.0f;
    #pragma unroll
    for (int k = 0; k < DIM / 4; ++k) {
        float4 t = ((const float4*)q)[k];
        float r0 = t.x - f[4*k+0];
        float r1 = t.y - f[4*k+1];
        float r2 = t.z - f[4*k+2];
        float r3 = t.w - f[4*k+3];
        dl = __builtin_fmaf(r0, r0, dl); dl = __builtin_fmaf(r1, r1, dl);
        dl = __builtin_fmaf(r2, r2, dl); dl = __builtin_fmaf(r3, r3, dl);
        ((float4*)(out + Q_OFF + (size_t)v * DIM))[k] = t;
    }

    // diff: wave reduce then one atomic per wave (2048 atomics total)
    #pragma unroll
    for (int off = 32; off > 0; off >>= 1) dl += __shfl_down(dl, off);
    if ((threadIdx.x & 63) == 0) atomicAdd(dsum, dl);
}

// ============ stats: one block per code; scan indices, gather x rows =====
// Index array (512 KB) is L2-resident across the scan; each x row is read
// exactly once device-wide (256 B aligned lines). No global atomics.
__global__ __launch_bounds__(256) void vq_stats(
    const float* __restrict__ x,
    const float* __restrict__ ind,     // out + IND_OFF (floats, small ints)
    float* __restrict__ counts,        // ws + CNT_OFF
    float* __restrict__ esum)          // ws + ESUM_OFF
{
    __shared__ float acc[DIM];
    __shared__ float cnt;
    int j = blockIdx.x;
    int t = threadIdx.x;
    if (t < DIM) acc[t] = 0.0f;
    if (t == 0)  cnt = 0.0f;
    __syncthreads();

    float jf = (float)j;
    for (int i = 0; i < NVEC / 256; ++i) {
        int v = i * 256 + t;                  // coalesced index read
        if (ind[v] == jf) {
            atomicAdd(&cnt, 1.0f);
            const float* fx = x + (size_t)v * DIM;
            #pragma unroll
            for (int k = 0; k < DIM / 4; ++k) {
                float4 q = ((const float4*)fx)[k];
                atomicAdd(&acc[4*k+0], q.x);
                atomicAdd(&acc[4*k+1], q.y);
                atomicAdd(&acc[4*k+2], q.z);
                atomicAdd(&acc[4*k+3], q.w);
            }
        }
    }
    __syncthreads();
    if (t < DIM) esum[j * DIM + t] = acc[t];
    if (t == 0)  counts[j] = cnt;
}

// ============ finalize: EMA updates + normalized codebook + diff ==========
__global__ __launch_bounds__(512) void vq_finalize(
    const float* __restrict__ cluster_size,
    const float* __restrict__ embed_avg,
    const float* __restrict__ ws,
    float* __restrict__ out)
{
    __shared__ float wsum[8];
    __shared__ float n_sh;
    int j = threadIdx.x;  // 512 threads, one per code

    float ncs = DECAYF * cluster_size[j] + OMDF * ws[CNT_OFF + j];
    out[NCS_OFF + j] = ncs;

    float s = ncs;
    #pragma unroll
    for (int off = 32; off > 0; off >>= 1) s += __shfl_down(s, off);
    if ((j & 63) == 0) wsum[j >> 6] = s;
    __syncthreads();
    if (j == 0) {
        float n = 0.f;
        #pragma unroll
        for (int w = 0; w < 8; ++w) n += wsum[w];
        n_sh = n;
        out[DIFF_OFF] = ws[DSUM_OFF] * (1.0f / 8388608.0f);  // 2^23: exact
    }
    __syncthreads();
    float n   = n_sh;
    float csz = (ncs + EPSF) / (n + (float)K * EPSF) * n;

    #pragma unroll 4
    for (int d = 0; d < DIM; ++d) {
        float ea = DECAYF * embed_avg[d * K + j] + OMDF * ws[ESUM_OFF + j * DIM + d];
        out[NEA_OFF + d * K + j] = ea;        // coalesced over j
        out[NE_OFF  + d * K + j] = ea / csz;
    }
}

// ============ launch ============
extern "C" void kernel_launch(void* const* d_in, const int* in_sizes, int n_in,
                              void* d_out, int out_size, void* d_ws, size_t ws_size,
                              hipStream_t stream) {
    const float* x            = (const float*)d_in[0];
    const float* embed        = (const float*)d_in[1];
    const float* cluster_size = (const float*)d_in[2];
    const float* embed_avg    = (const float*)d_in[3];
    float* out = (float*)d_out;
    float* ws  = (float*)d_ws;

    // zero only the diff accumulator (ws is poisoned 0xAA each call)
    hipMemsetAsync(ws + DSUM_OFF, 0, sizeof(float), stream);

    vq_prep<<<K / 256, 256, 0, stream>>>(embed, ws);
    vq_assign<<<NVEC / 256, 256, 0, stream>>>(
        x, ws + ET_OFF, ws + C_OFF, ws + DSUM_OFF, out);
    vq_stats<<<K, 256, 0, stream>>>(
        x, out + IND_OFF, ws + CNT_OFF, ws + ESUM_OFF);
    vq_finalize<<<1, K, 0, stream>>>(cluster_size, embed_avg, ws, out);
}

// Round 4
// 379.787 us; speedup vs baseline: 4.1173x; 4.1173x over previous
//
#include <hip/hip_runtime.h>

// ---------------- problem constants ----------------
#define NVEC  131072      // 32*4096 vectors
#define DIM   64
#define K     512
#define DECAYF 0.99f
#define OMDF   0.01f
#define EPSF   1e-5f
#define NBLK_ASSIGN (NVEC / 64)   // 2048 blocks, 64 vectors each

// ---------------- output layout (floats, concatenated in return order) ----
#define Q_OFF    0
#define DIFF_OFF 8388608
#define IND_OFF  8388609
#define NE_OFF   8519681
#define NCS_OFF  8552449
#define NEA_OFF  8552961

// ---------------- ws layout (floats) ----------------
#define ET_OFF    0        // E^T : K x DIM  (code rows contiguous)
#define C_OFF     32768    // np-order sum(E*E, axis=0) : K
#define CNT_OFF   33280    // histogram : K           (written by vq_reduce)
#define ESUM_OFF  33792    // segment sum : K x DIM   (written by vq_reduce)
#define DPART_OFF 66560    // per-assign-block diff partials : 2048
#define PART_OFF  68864    // scatter partials : SBLK * (32768 + 512)

// ============ prep: transpose embed -> E^T, C_j = np.sum(E*E, axis=0) ====
__global__ __launch_bounds__(256) void vq_prep(const float* __restrict__ embed,
                                               float* __restrict__ ws) {
    #pragma clang fp contract(off)
    int j = blockIdx.x * 256 + threadIdx.x;   // code index, 0..511
    float c = 0.0f;
    for (int d = 0; d < DIM; ++d) {
        float v = embed[d * K + j];           // coalesced across j
        ws[ET_OFF + j * DIM + d] = v;
        float t = v * v;
        c = c + t;
    }
    ws[C_OFF + j] = c;
}

// ============ main: np-fp32-replica argmin, 4-way K-split ================
// Block = 4 waves x 64 vectors. Wave w scans codes [w*128, (w+1)*128).
// Per-j arithmetic is bit-identical to the round-2 passing kernel; the
// 4-way combine is lexicographic (dist, idx) min == numpy first-min.
__global__ __launch_bounds__(256) void vq_assign(
    const float* __restrict__ x,
    const float* __restrict__ ET,      // ws + ET_OFF
    const float* __restrict__ C,       // ws + C_OFF
    float* __restrict__ dpart,         // ws + DPART_OFF
    float* __restrict__ out)
{
    #pragma clang fp contract(off)
    __shared__ float sd[4][64];
    __shared__ int   si[4][64];
    __shared__ int   sbest[64];
    __shared__ float wdl[4];

    int lane = threadIdx.x & 63;
    int wq   = __builtin_amdgcn_readfirstlane(threadIdx.x >> 6); // wave-uniform
    int v    = blockIdx.x * 64 + lane;
    const float* fx = x + (size_t)v * DIM;

    float f[DIM];
    #pragma unroll
    for (int k = 0; k < DIM / 4; ++k) {
        float4 t = ((const float4*)fx)[k];
        f[4*k+0] = t.x; f[4*k+1] = t.y; f[4*k+2] = t.z; f[4*k+3] = t.w;
    }

    // A = np.sum(f*f, axis=1): numpy pairwise, n=64 -> 8 accumulators over
    // strides of 8, then ((r0+r1)+(r2+r3))+((r4+r5)+(r6+r7)). Plain mul+add.
    float r[8];
    #pragma unroll
    for (int k = 0; k < 8; ++k) r[k] = f[k] * f[k];
    #pragma unroll
    for (int b = 1; b < 8; ++b) {
        #pragma unroll
        for (int k = 0; k < 8; ++k) {
            float t = f[8*b + k] * f[8*b + k];
            r[k] = r[k] + t;
        }
    }
    float A = ((r[0] + r[1]) + (r[2] + r[3])) + ((r[4] + r[5]) + (r[6] + r[7]));

    // scan this wave's 128 codes; j wave-uniform -> scalar s_loads for e,C
    const float* eseg = ET + (size_t)wq * 128 * DIM;
    const float* Cseg = C + wq * 128;
    float bestd = 3.0e38f;
    int   besti = wq * 128;
    #pragma unroll 8
    for (int jj = 0; jj < 128; ++jj) {
        const float* e = eseg + jj * DIM;
        float m = 0.0f;
        #pragma unroll
        for (int d = 0; d < DIM; ++d) m = __builtin_fmaf(f[d], e[d], m);
        float t1 = 2.0f * m;             // exact (x2)
        float t2 = A - t1;               // rounded at ulp(~64)
        float dist = t2 + Cseg[jj];      // rounded
        if (dist < bestd) { bestd = dist; besti = wq * 128 + jj; }
    }

    sd[wq][lane] = bestd;
    si[wq][lane] = besti;
    __syncthreads();

    if (wq == 0) {
        float bd = sd[0][lane];
        int   bi = si[0][lane];
        #pragma unroll
        for (int q = 1; q < 4; ++q) {
            float d2 = sd[q][lane];
            int   i2 = si[q][lane];
            if (d2 < bd || (d2 == bd && i2 < bi)) { bd = d2; bi = i2; }
        }
        sbest[lane] = bi;
        out[IND_OFF + v] = (float)bi;    // coalesced, 64 lanes
    }
    __syncthreads();

    // epilogue: wave w handles 16-float quarter of each row
    int bi = sbest[lane];
    const float* qrow = ET + (size_t)bi * DIM + wq * 16;
    const float* xrow = fx + wq * 16;                     // L1-hot reload
    float* orow = out + Q_OFF + (size_t)v * DIM + wq * 16;
    float dl = 0.0f;
    #pragma unroll
    for (int k = 0; k < 4; ++k) {
        float4 tq = ((const float4*)qrow)[k];
        float4 tx = ((const float4*)xrow)[k];
        float r0 = tq.x - tx.x;
        float r1 = tq.y - tx.y;
        float r2 = tq.z - tx.z;
        float r3 = tq.w - tx.w;
        dl = __builtin_fmaf(r0, r0, dl); dl = __builtin_fmaf(r1, r1, dl);
        dl = __builtin_fmaf(r2, r2, dl); dl = __builtin_fmaf(r3, r3, dl);
        ((float4*)orow)[k] = tq;
    }

    // deterministic diff partial: wave reduce, then block reduce -> dpart
    #pragma unroll
    for (int off = 32; off > 0; off >>= 1) dl += __shfl_down(dl, off);
    if (lane == 0) wdl[wq] = dl;
    __syncthreads();
    if (threadIdx.x == 0)
        dpart[blockIdx.x] = ((wdl[0] + wdl[1]) + (wdl[2] + wdl[3]));
}

// ============ scatter: block-private LDS table, no divergence ============
// Each block owns vpb contiguous vectors. Table stride 65 (col 64 = count)
// randomizes banks: bank = (j + d) % 32 with random j => ~2-way (free).
__global__ __launch_bounds__(256) void vq_scatter(
    const float* __restrict__ x,
    const float* __restrict__ ind,     // out + IND_OFF
    float* __restrict__ partE,         // ws + PART_OFF          [SBLK][32768]
    float* __restrict__ partC,         // ws + PART_OFF + SBLK*32768  [SBLK][512]
    int vpb)
{
    __shared__ float tab[K * 65];      // 133,120 B (gfx950: 160 KB/WG max)
    int t = threadIdx.x;
    int p = blockIdx.x;

    for (int i = t; i < K * 65; i += 256) tab[i] = 0.0f;
    __syncthreads();

    int base = p * vpb;
    for (int i = 0; i < vpb; i += 256) {
        int v = base + i + t;
        int j = (int)ind[v];                   // coalesced
        float* row = tab + j * 65;
        atomicAdd(row + 64, 1.0f);
        const float* fxv = x + (size_t)v * DIM;
        #pragma unroll
        for (int k = 0; k < DIM / 4; ++k) {
            float4 q = ((const float4*)fxv)[k];
            atomicAdd(row + 4*k + 0, q.x);
            atomicAdd(row + 4*k + 1, q.y);
            atomicAdd(row + 4*k + 2, q.z);
            atomicAdd(row + 4*k + 3, q.w);
        }
    }
    __syncthreads();

    for (int idx = t; idx < K * DIM; idx += 256) {
        int j = idx >> 6, d = idx & 63;
        partE[(size_t)p * (K * DIM) + idx] = tab[j * 65 + d];
    }
    for (int j = t; j < K; j += 256)
        partC[p * K + j] = tab[j * 65 + 64];
}

// ============ reduce partials -> esum, counts ============
__global__ __launch_bounds__(256) void vq_reduce(
    const float* __restrict__ partE,
    const float* __restrict__ partC,
    float* __restrict__ counts,        // ws + CNT_OFF
    float* __restrict__ esum,          // ws + ESUM_OFF
    int P)
{
    int gid = blockIdx.x * 256 + threadIdx.x;
    if (gid < K * DIM) {
        float s = 0.0f;
        for (int p = 0; p < P; ++p) s += partE[(size_t)p * (K * DIM) + gid];
        esum[gid] = s;
    } else if (gid < K * DIM + K) {
        int j = gid - K * DIM;
        float s = 0.0f;
        for (int p = 0; p < P; ++p) s += partC[p * K + j];
        counts[j] = s;
    }
}

// ============ finalize: EMA updates + normalized codebook + diff ==========
__global__ __launch_bounds__(512) void vq_finalize(
    const float* __restrict__ cluster_size,
    const float* __restrict__ embed_avg,
    const float* __restrict__ ws,
    float* __restrict__ out)
{
    __shared__ float wsum[8];
    __shared__ float dsum_sh[8];
    __shared__ float n_sh;
    int j = threadIdx.x;  // 512 threads, one per code

    float ncs = DECAYF * cluster_size[j] + OMDF * ws[CNT_OFF + j];
    out[NCS_OFF + j] = ncs;

    // diff: sum 2048 block partials (deterministic)
    float dsum = 0.0f;
    #pragma unroll
    for (int k = 0; k < NBLK_ASSIGN / 512; ++k)
        dsum += ws[DPART_OFF + k * 512 + j];

    float s = ncs;
    #pragma unroll
    for (int off = 32; off > 0; off >>= 1) {
        s    += __shfl_down(s, off);
        dsum += __shfl_down(dsum, off);
    }
    if ((j & 63) == 0) { wsum[j >> 6] = s; dsum_sh[j >> 6] = dsum; }
    __syncthreads();
    if (j == 0) {
        float n = 0.f, dtot = 0.f;
        #pragma unroll
        for (int w = 0; w < 8; ++w) { n += wsum[w]; dtot += dsum_sh[w]; }
        n_sh = n;
        out[DIFF_OFF] = dtot * (1.0f / 8388608.0f);  // 2^23: exact
    }
    __syncthreads();
    float n   = n_sh;
    float csz = (ncs + EPSF) / (n + (float)K * EPSF) * n;

    #pragma unroll 4
    for (int d = 0; d < DIM; ++d) {
        float ea = DECAYF * embed_avg[d * K + j] + OMDF * ws[ESUM_OFF + j * DIM + d];
        out[NEA_OFF + d * K + j] = ea;        // coalesced over j
        out[NE_OFF  + d * K + j] = ea / csz;
    }
}

// ============ launch ============
extern "C" void kernel_launch(void* const* d_in, const int* in_sizes, int n_in,
                              void* d_out, int out_size, void* d_ws, size_t ws_size,
                              hipStream_t stream) {
    const float* x            = (const float*)d_in[0];
    const float* embed        = (const float*)d_in[1];
    const float* cluster_size = (const float*)d_in[2];
    const float* embed_avg    = (const float*)d_in[3];
    float* out = (float*)d_out;
    float* ws  = (float*)d_ws;

    // pick largest partial-count that fits in ws
    int SBLK = 8;
    for (int cand = 128; cand >= 8; cand >>= 1) {
        size_t need = (size_t)(PART_OFF + cand * (K * DIM + K)) * sizeof(float);
        if (need <= ws_size) { SBLK = cand; break; }
    }
    int vpb = NVEC / SBLK;
    float* partE = ws + PART_OFF;
    float* partC = ws + PART_OFF + (size_t)SBLK * (K * DIM);

    vq_prep<<<K / 256, 256, 0, stream>>>(embed, ws);
    vq_assign<<<NBLK_ASSIGN, 256, 0, stream>>>(
        x, ws + ET_OFF, ws + C_OFF, ws + DPART_OFF, out);
    vq_scatter<<<SBLK, 256, 0, stream>>>(
        x, out + IND_OFF, partE, partC, vpb);
    vq_reduce<<<(K * DIM + K + 255) / 256, 256, 0, stream>>>(
        partE, partC, ws + CNT_OFF, ws + ESUM_OFF, SBLK);
    vq_finalize<<<1, K, 0, stream>>>(cluster_size, embed_avg, ws, out);
}

// Round 5
// 358.114 us; speedup vs baseline: 4.3664x; 1.0605x over previous
//
#include <hip/hip_runtime.h>

// ---------------- problem constants ----------------
#define NVEC  131072      // 32*4096 vectors
#define DIM   64
#define K     512
#define DECAYF 0.99f
#define OMDF   0.01f
#define EPSF   1e-5f
#define NBLK_ASSIGN (NVEC / 64)   // 2048 blocks, 64 vectors each

// ---------------- output layout (floats, concatenated in return order) ----
#define Q_OFF    0
#define DIFF_OFF 8388608
#define IND_OFF  8388609
#define NE_OFF   8519681
#define NCS_OFF  8552449
#define NEA_OFF  8552961

// ---------------- ws layout (floats) — total 331,264 floats = 1.33 MB ----
#define ET_OFF    0        // E^T : K x DIM
#define C_OFF     32768    // np-order sum(E*E, axis=0) : K
#define CNT_OFF   33280    // histogram totals : K      (written by vq_scan)
#define ESUM_OFF  33792    // segment sum : K x DIM     (written by vq_esum)
#define DPART_OFF 66560    // per-assign-block diff partials : 2048
#define HIST_OFF  68608    // per-block hist / start offsets : 256 x 512
#define BASE_OFF  199680   // bucket base per code : 512 (int)
#define BUCK_OFF  200192   // bucketed vector ids : NVEC (int)

// ============ prep: transpose embed -> E^T, C_j = np.sum(E*E, axis=0) ====
__global__ __launch_bounds__(256) void vq_prep(const float* __restrict__ embed,
                                               float* __restrict__ ws) {
    #pragma clang fp contract(off)
    int j = blockIdx.x * 256 + threadIdx.x;
    float c = 0.0f;
    for (int d = 0; d < DIM; ++d) {
        float v = embed[d * K + j];           // coalesced across j
        ws[ET_OFF + j * DIM + d] = v;
        float t = v * v;
        c = c + t;
    }
    ws[C_OFF + j] = c;
}

// ============ main: np-fp32-replica argmin, 4-way K-split ================
// Block = 4 waves x 64 vectors; wave w scans codes [w*128,(w+1)*128).
// __launch_bounds__(256,4): 128-VGPR cap so f[64] stays register-resident
// (r4's default cap of 64 forced L1 reloads of x inside the j-loop).
__global__ __launch_bounds__(256, 4) void vq_assign(
    const float* __restrict__ x,
    const float* __restrict__ ET,      // ws + ET_OFF
    const float* __restrict__ C,       // ws + C_OFF
    float* __restrict__ dpart,         // ws + DPART_OFF
    float* __restrict__ out)
{
    #pragma clang fp contract(off)
    __shared__ float sd[4][64];
    __shared__ int   si[4][64];
    __shared__ int   sbest[64];
    __shared__ float wdl[4];

    int lane = threadIdx.x & 63;
    int wq   = __builtin_amdgcn_readfirstlane(threadIdx.x >> 6); // wave-uniform
    int v    = blockIdx.x * 64 + lane;
    const float* fx = x + (size_t)v * DIM;

    float f[DIM];
    #pragma unroll
    for (int k = 0; k < DIM / 4; ++k) {
        float4 t = ((const float4*)fx)[k];
        f[4*k+0] = t.x; f[4*k+1] = t.y; f[4*k+2] = t.z; f[4*k+3] = t.w;
    }

    // A = np.sum(f*f, axis=1): numpy pairwise, n=64 -> 8 accumulators over
    // strides of 8, then ((r0+r1)+(r2+r3))+((r4+r5)+(r6+r7)). Plain mul+add.
    float r[8];
    #pragma unroll
    for (int k = 0; k < 8; ++k) r[k] = f[k] * f[k];
    #pragma unroll
    for (int b = 1; b < 8; ++b) {
        #pragma unroll
        for (int k = 0; k < 8; ++k) {
            float t = f[8*b + k] * f[8*b + k];
            r[k] = r[k] + t;
        }
    }
    float A = ((r[0] + r[1]) + (r[2] + r[3])) + ((r[4] + r[5]) + (r[6] + r[7]));

    // scan this wave's 128 codes; j wave-uniform -> scalar s_loads for e,C.
    // Per-j fp32 sequence bit-identical to round-2 passing kernel.
    const float* eseg = ET + (size_t)wq * 128 * DIM;
    const float* Cseg = C + wq * 128;
    float bestd = 3.0e38f;
    int   besti = wq * 128;
    #pragma unroll 4
    for (int jj = 0; jj < 128; ++jj) {
        const float* e = eseg + jj * DIM;
        float m = 0.0f;
        #pragma unroll
        for (int d = 0; d < DIM; ++d) m = __builtin_fmaf(f[d], e[d], m);
        float t1 = 2.0f * m;             // exact (x2)
        float t2 = A - t1;               // rounded at ulp(~64)
        float dist = t2 + Cseg[jj];      // rounded
        if (dist < bestd) { bestd = dist; besti = wq * 128 + jj; }
    }

    sd[wq][lane] = bestd;
    si[wq][lane] = besti;
    __syncthreads();

    if (wq == 0) {
        float bd = sd[0][lane];
        int   bi = si[0][lane];
        #pragma unroll
        for (int q = 1; q < 4; ++q) {
            float d2 = sd[q][lane];
            int   i2 = si[q][lane];
            if (d2 < bd || (d2 == bd && i2 < bi)) { bd = d2; bi = i2; }
        }
        sbest[lane] = bi;
        out[IND_OFF + v] = (float)bi;    // coalesced
    }
    __syncthreads();

    // epilogue: wave w handles a 16-float quarter of each row
    int bi = sbest[lane];
    const float* qrow = ET + (size_t)bi * DIM + wq * 16;
    const float* xrow = fx + wq * 16;                     // L1-hot reload
    float* orow = out + Q_OFF + (size_t)v * DIM + wq * 16;
    float dl = 0.0f;
    #pragma unroll
    for (int k = 0; k < 4; ++k) {
        float4 tq = ((const float4*)qrow)[k];
        float4 tx = ((const float4*)xrow)[k];
        float r0 = tq.x - tx.x;
        float r1 = tq.y - tx.y;
        float r2 = tq.z - tx.z;
        float r3 = tq.w - tx.w;
        dl = __builtin_fmaf(r0, r0, dl); dl = __builtin_fmaf(r1, r1, dl);
        dl = __builtin_fmaf(r2, r2, dl); dl = __builtin_fmaf(r3, r3, dl);
        ((float4*)orow)[k] = tq;
    }

    #pragma unroll
    for (int off = 32; off > 0; off >>= 1) dl += __shfl_down(dl, off);
    if (lane == 0) wdl[wq] = dl;
    __syncthreads();
    if (threadIdx.x == 0)
        dpart[blockIdx.x] = ((wdl[0] + wdl[1]) + (wdl[2] + wdl[3]));
}

// ============ stats stage 1: per-block histogram (256 blocks x 512 vecs) ==
__global__ __launch_bounds__(256) void vq_hist(
    const float* __restrict__ ind,     // out + IND_OFF
    float* __restrict__ hist)          // ws + HIST_OFF  [256][512]
{
    __shared__ float h[K];
    int t = threadIdx.x;
    h[t] = 0.0f; h[t + 256] = 0.0f;
    __syncthreads();
    int base = blockIdx.x * 512;
    #pragma unroll
    for (int i = 0; i < 512; i += 256) {
        int j = (int)ind[base + i + t];
        atomicAdd(&h[j], 1.0f);        // LDS atomic
    }
    __syncthreads();
    hist[blockIdx.x * K + t]       = h[t];
    hist[blockIdx.x * K + t + 256] = h[t + 256];
}

// ============ stats stage 2: totals + exclusive scan + start offsets ======
// In-place transform: hist[b][j] (float count) -> start slot (int).
__global__ __launch_bounds__(512) void vq_scan(
    float* __restrict__ hist,          // ws + HIST_OFF (in-place -> int)
    float* __restrict__ counts,        // ws + CNT_OFF
    int*   __restrict__ baseI)         // ws + BASE_OFF
{
    __shared__ int sc[K];
    int j = threadIdx.x;

    float s = 0.0f;
    for (int b = 0; b < 256; ++b) s += hist[b * K + j];  // coalesced over j
    counts[j] = s;

    // exclusive scan over codes (Hillis-Steele inclusive, then subtract)
    int ci = (int)s;
    sc[j] = ci;
    __syncthreads();
    for (int off = 1; off < K; off <<= 1) {
        int t = (j >= off) ? sc[j - off] : 0;
        __syncthreads();
        sc[j] += t;
        __syncthreads();
    }
    int base = sc[j] - ci;
    baseI[j] = base;

    // pass 2: per-block running starts, written in place as int
    int* histI = (int*)hist;
    int run = base;
    for (int b = 0; b < 256; ++b) {
        int h = (int)hist[b * K + j];
        histI[b * K + j] = run;
        run += h;
    }
}

// ============ stats stage 3: bucket vector ids by code ====================
__global__ __launch_bounds__(256) void vq_bucket(
    const float* __restrict__ ind,
    const int* __restrict__ histI,     // start offsets [256][512]
    int* __restrict__ buckI)           // ws + BUCK_OFF
{
    __shared__ int ofs[K];
    int t = threadIdx.x;
    ofs[t]       = histI[blockIdx.x * K + t];
    ofs[t + 256] = histI[blockIdx.x * K + t + 256];
    __syncthreads();
    int base = blockIdx.x * 512;
    #pragma unroll
    for (int i = 0; i < 512; i += 256) {
        int v = base + i + t;
        int j = (int)ind[v];
        int slot = atomicAdd(&ofs[j], 1);  // LDS atomic, returns old
        buckI[slot] = v;
    }
}

// ============ stats stage 4: dense per-code gather-sum ====================
// Block = code j, 4 waves; wave w sums rows r = w, w+4, ... Each x row is
// read exactly once device-wide, 256 B coalesced. No global atomics.
__global__ __launch_bounds__(256) void vq_esum(
    const float* __restrict__ x,
    const int* __restrict__ buckI,
    const int* __restrict__ baseI,
    const float* __restrict__ counts,
    float* __restrict__ esum)          // ws + ESUM_OFF
{
    __shared__ float p[4][DIM];
    int j = blockIdx.x;
    int d = threadIdx.x & 63;
    int w = __builtin_amdgcn_readfirstlane(threadIdx.x >> 6);
    int beg = baseI[j];
    int cnt = (int)counts[j];

    float acc = 0.0f;
    for (int r = w; r < cnt; r += 4) {
        int v = buckI[beg + r];                   // wave-uniform -> s_load
        acc += x[(size_t)v * DIM + d];            // 256 B coalesced line
    }
    p[w][d] = acc;
    __syncthreads();
    if (w == 0)
        esum[j * DIM + d] = ((p[0][d] + p[1][d]) + (p[2][d] + p[3][d]));
}

// ============ finalize: EMA updates + normalized codebook + diff ==========
__global__ __launch_bounds__(512) void vq_finalize(
    const float* __restrict__ cluster_size,
    const float* __restrict__ embed_avg,
    const float* __restrict__ ws,
    float* __restrict__ out)
{
    __shared__ float wsum[8];
    __shared__ float dsum_sh[8];
    __shared__ float n_sh;
    int j = threadIdx.x;  // 512 threads, one per code

    float ncs = DECAYF * cluster_size[j] + OMDF * ws[CNT_OFF + j];
    out[NCS_OFF + j] = ncs;

    // diff: sum 2048 block partials (deterministic)
    float dsum = 0.0f;
    #pragma unroll
    for (int k = 0; k < NBLK_ASSIGN / 512; ++k)
        dsum += ws[DPART_OFF + k * 512 + j];

    float s = ncs;
    #pragma unroll
    for (int off = 32; off > 0; off >>= 1) {
        s    += __shfl_down(s, off);
        dsum += __shfl_down(dsum, off);
    }
    if ((j & 63) == 0) { wsum[j >> 6] = s; dsum_sh[j >> 6] = dsum; }
    __syncthreads();
    if (j == 0) {
        float n = 0.f, dtot = 0.f;
        #pragma unroll
        for (int w = 0; w < 8; ++w) { n += wsum[w]; dtot += dsum_sh[w]; }
        n_sh = n;
        out[DIFF_OFF] = dtot * (1.0f / 8388608.0f);  // 2^23: exact
    }
    __syncthreads();
    float n   = n_sh;
    float csz = (ncs + EPSF) / (n + (float)K * EPSF) * n;

    #pragma unroll 4
    for (int d = 0; d < DIM; ++d) {
        float ea = DECAYF * embed_avg[d * K + j] + OMDF * ws[ESUM_OFF + j * DIM + d];
        out[NEA_OFF + d * K + j] = ea;        // coalesced over j
        out[NE_OFF  + d * K + j] = ea / csz;
    }
}

// ============ launch ============
extern "C" void kernel_launch(void* const* d_in, const int* in_sizes, int n_in,
                              void* d_out, int out_size, void* d_ws, size_t ws_size,
                              hipStream_t stream) {
    const float* x            = (const float*)d_in[0];
    const float* embed        = (const float*)d_in[1];
    const float* cluster_size = (const float*)d_in[2];
    const float* embed_avg    = (const float*)d_in[3];
    float* out = (float*)d_out;
    float* ws  = (float*)d_ws;

    float* hist  = ws + HIST_OFF;
    int*   baseI = (int*)(ws + BASE_OFF);
    int*   buckI = (int*)(ws + BUCK_OFF);

    vq_prep<<<K / 256, 256, 0, stream>>>(embed, ws);
    vq_assign<<<NBLK_ASSIGN, 256, 0, stream>>>(
        x, ws + ET_OFF, ws + C_OFF, ws + DPART_OFF, out);
    vq_hist<<<NVEC / 512, 256, 0, stream>>>(out + IND_OFF, hist);
    vq_scan<<<1, 512, 0, stream>>>(hist, ws + CNT_OFF, baseI);
    vq_bucket<<<NVEC / 512, 256, 0, stream>>>(out + IND_OFF, (const int*)hist, buckI);
    vq_esum<<<K, 256, 0, stream>>>(x, buckI, baseI, ws + CNT_OFF, ws + ESUM_OFF);
    vq_finalize<<<1, K, 0, stream>>>(cluster_size, embed_avg, ws, out);
}